// Round 9
// baseline (247.523 us; speedup 1.0000x reference)
//
#include <hip/hip_runtime.h>
#include <stdint.h>

typedef uint32_t u32;
typedef uint64_t u64;
typedef uint8_t  u8;

#define KEY_MIN   0x3C000000u   /* conf = max softmax >= 1/C = 0.01 > 2^-7 */
#define SUBSHIFT  10
#define NBUCK     57344         /* (0x3F800000 - 0x3C000000) >> 10 */
#define NBINS     20
#define NB        19
#define LISTCAP   2048          /* boundary-bucket keys; expected ~720 */

__device__ __forceinline__ u32 bucket_of(u32 key) {
    if (key < KEY_MIN) return 0u;
    u32 b = (key - KEY_MIN) >> SUBSHIFT;
    return b < (u32)NBUCK ? b : (u32)(NBUCK - 1);
}

// ---------------- K1 (C==100): 16 lanes per row, coalesced (R4 champion) ------
__global__ __launch_bounds__(256) void k1_conf100(
        const float* __restrict__ logits, const int* __restrict__ labels,
        u32* __restrict__ keys, u8* __restrict__ accb, u32* __restrict__ hist,
        int N) {
    const int C4 = 25;
    int lane = threadIdx.x & 63;
    int wid  = (blockIdx.x * (blockDim.x >> 6)) + (threadIdx.x >> 6);
    int g    = lane >> 4;
    int sub  = lane & 15;
    int r    = wid * 4 + g;
    if (r >= N) return;

    const float4* row4 = (const float4*)(logits + (size_t)r * 100);
    float4 v0 = row4[sub];
    float4 v1;
    bool has2 = (sub + 16) < C4;
    if (has2) v1 = row4[sub + 16];
    else      v1 = make_float4(-3.4e38f, -3.4e38f, -3.4e38f, -3.4e38f);

    float m = v0.x; int am = 4 * sub;
    if (v0.y > m) { m = v0.y; am = 4 * sub + 1; }
    if (v0.z > m) { m = v0.z; am = 4 * sub + 2; }
    if (v0.w > m) { m = v0.w; am = 4 * sub + 3; }
    int b2 = 64 + 4 * sub;
    if (v1.x > m) { m = v1.x; am = b2; }
    if (v1.y > m) { m = v1.y; am = b2 + 1; }
    if (v1.z > m) { m = v1.z; am = b2 + 2; }
    if (v1.w > m) { m = v1.w; am = b2 + 3; }

    #pragma unroll
    for (int off = 8; off >= 1; off >>= 1) {
        float om = __shfl_xor(m, off);
        int   oa = __shfl_xor(am, off);
        if (om > m || (om == m && oa < am)) { m = om; am = oa; }
    }

    float s = __expf(v0.x - m) + __expf(v0.y - m) + __expf(v0.z - m) + __expf(v0.w - m);
    if (has2) s += __expf(v1.x - m) + __expf(v1.y - m) + __expf(v1.z - m) + __expf(v1.w - m);
    #pragma unroll
    for (int off = 8; off >= 1; off >>= 1) s += __shfl_xor(s, off);

    if (sub == 0) {
        float conf = 1.0f / s;
        u32 key = __float_as_uint(conf);
        keys[r] = key;
        accb[r] = (labels[r] == am) ? (u8)1 : (u8)0;
        atomicAdd(&hist[bucket_of(key)], 1u);
    }
}

// ---------------- K1 generic fallback -----------------------------------------
__global__ __launch_bounds__(256) void k1_generic(
        const float* __restrict__ logits, const int* __restrict__ labels,
        u32* __restrict__ keys, u8* __restrict__ accb, u32* __restrict__ hist,
        int N, int C) {
    int i = blockIdx.x * blockDim.x + threadIdx.x;
    if (i >= N) return;
    const float* row = logits + (size_t)i * (size_t)C;
    float m = -3.4e38f, s = 0.f;
    int am = 0;
    for (int c = 0; c < C; c++) {
        float v = row[c];
        float nm = fmaxf(m, v); am = (v > m) ? c : am;
        s = s * __expf(m - nm) + __expf(v - nm); m = nm;
    }
    float conf = 1.0f / s;
    u32 key = __float_as_uint(conf);
    keys[i] = key;
    accb[i] = (labels[i] == am) ? (u8)1 : (u8)0;
    atomicAdd(&hist[bucket_of(key)], 1u);
}

// meta: 0..18 bBucket | 19..37 bOff
// ---------------- K2: scan histogram (R4 scalar, 1 block) ---------------------
__global__ void k2_scan(const u32* __restrict__ hist, u32* __restrict__ meta,
                        u32 W) {
    __shared__ u32 sp[1024];
    int t = threadIdx.x;
    const int PER = NBUCK / 1024;  // 56
    u32 s = 0;
    for (int k = 0; k < PER; k++) s += hist[t * PER + k];
    sp[t] = s; __syncthreads();
    for (int d = 1; d < 1024; d <<= 1) {
        u32 v = (t >= d) ? sp[t - d] : 0u;
        __syncthreads();
        sp[t] += v;
        __syncthreads();
    }
    u32 cum = sp[t] - s;  // exclusive prefix over this thread's 56 buckets
    for (int k = 0; k < PER; k++) {
        u32 c = hist[t * PER + k];
        if (c) {
            for (int j = 0; j < NB; j++) {
                u32 r = (u32)(j + 1) * W;
                if (cum < r && r <= cum + c) {
                    meta[j] = (u32)(t * PER + k);   // boundary bucket
                    meta[NB + j] = r - cum;         // rank of boundary within bucket (>=1)
                }
            }
        }
        cum += c;
    }
}

// ---------------- K37: single pass — bin non-boundary keys, buffer the rest ---
__global__ __launch_bounds__(256) void k37_accum(
        const u32* __restrict__ keys, const u8* __restrict__ accb,
        const u32* __restrict__ meta, u64* __restrict__ confQ,
        u32* __restrict__ accCnt, u64* __restrict__ list, u32* __restrict__ listCnt,
        int N) {
    __shared__ unsigned long long lc[4][NBINS];
    __shared__ u32 la[4][NBINS];
    __shared__ u32 sB[NB];
    int t = threadIdx.x;
    int w = t >> 6;
    if (t < 4 * NBINS) { lc[t / NBINS][t % NBINS] = 0ull; la[t / NBINS][t % NBINS] = 0u; }
    if (t < NB) sB[t] = meta[t];
    __syncthreads();
    int total4 = N >> 2;
    const uint4*  k4 = (const uint4*)keys;
    const uchar4* a4 = (const uchar4*)accb;
    for (int i = blockIdx.x * blockDim.x + t; i < total4; i += gridDim.x * blockDim.x) {
        uint4  kv = k4[i];
        uchar4 av = a4[i];
        u32 ks[4] = {kv.x, kv.y, kv.z, kv.w};
        u32 as[4] = {av.x, av.y, av.z, av.w};
        #pragma unroll
        for (int e = 0; e < 4; e++) {
            u32 b = bucket_of(ks[e]);
            int bin = 0; bool isB = false;
            #pragma unroll
            for (int j = 0; j < NB; j++) {
                bin += (b > sB[j]) ? 1 : 0;
                isB |= (b == sB[j]);
            }
            if (isB) {
                u32 p = atomicAdd(listCnt, 1u);
                if (p < (u32)LISTCAP) list[p] = ((u64)ks[e] << 1) | (u64)as[e];
            } else {
                u64 q = (u64)(__uint_as_float(ks[e]) * 4294967296.0f);  // exact shift
                atomicAdd(&lc[w][bin], (unsigned long long)q);
                atomicAdd(&la[w][bin], as[e]);
            }
        }
    }
    for (int i = (total4 << 2) + blockIdx.x * blockDim.x + t; i < N;
         i += gridDim.x * blockDim.x) {
        u32 k = keys[i];
        u32 ac = (u32)accb[i];
        u32 b = bucket_of(k);
        int bin = 0; bool isB = false;
        for (int j = 0; j < NB; j++) { bin += (b > sB[j]) ? 1 : 0; isB |= (b == sB[j]); }
        if (isB) {
            u32 p = atomicAdd(listCnt, 1u);
            if (p < (u32)LISTCAP) list[p] = ((u64)k << 1) | (u64)ac;
        } else {
            u64 q = (u64)(__uint_as_float(k) * 4294967296.0f);
            atomicAdd(&lc[w][bin], (unsigned long long)q);
            atomicAdd(&la[w][bin], ac);
        }
    }
    __syncthreads();
    if (t < NBINS) {
        unsigned long long cq = lc[0][t] + lc[1][t] + lc[2][t] + lc[3][t];
        u32 ac = la[0][t] + la[1][t] + la[2][t] + la[3][t];
        if (cq) atomicAdd((unsigned long long*)&confQ[t], cq);
        if (ac) atomicAdd(&accCnt[t], ac);
    }
}

// ---------------- K48: sort boundary list, resolve thresholds, finish ECE -----
__global__ __launch_bounds__(256) void k48_final(
        const u64* __restrict__ list, const u32* __restrict__ listCnt,
        const u32* __restrict__ meta, const u64* __restrict__ confQ,
        const u32* __restrict__ accCnt, float* __restrict__ out, u32 W, int N) {
    __shared__ u64 S[LISTCAP];           // 16 KB
    __shared__ u32 sB[NB], sOff[NB], sKj[NB];
    __shared__ unsigned long long bc[NBINS];
    __shared__ u32 ba[NBINS];
    int t = threadIdx.x;
    u32 cnt = *listCnt; if (cnt > (u32)LISTCAP) cnt = LISTCAP;
    for (int i = t; i < LISTCAP; i += 256) S[i] = (i < (int)cnt) ? list[i] : ~0ull;
    if (t < NB) { sB[t] = meta[t]; sOff[t] = meta[NB + t]; }
    if (t < NBINS) { bc[t] = 0ull; ba[t] = 0u; }
    __syncthreads();

    // bitonic sort S ascending (sort by packed u64; key is bits [32:1])
    for (int k = 2; k <= LISTCAP; k <<= 1) {
        for (int j = k >> 1; j > 0; j >>= 1) {
            for (int i = t; i < LISTCAP; i += 256) {
                int ix = i ^ j;
                if (ix > i) {
                    u64 a = S[i], b = S[ix];
                    bool up = ((i & k) == 0);
                    if ((a > b) == up) { S[i] = b; S[ix] = a; }
                }
            }
            __syncthreads();
        }
    }

    // threshold K_j = sOff[j]-th smallest key among entries in bucket sB[j]
    if (t < NB) {
        u32 lo = 0, hi = cnt;
        while (lo < hi) {                 // lower_bound on bucket id
            u32 mid = (lo + hi) >> 1;
            u32 kk = (u32)(S[mid] >> 1);
            if (bucket_of(kk) < sB[t]) lo = mid + 1; else hi = mid;
        }
        u32 pos = lo + sOff[t] - 1;
        if (pos >= cnt) pos = cnt ? cnt - 1 : 0;   // guard (shouldn't trigger)
        sKj[t] = (u32)(S[pos] >> 1);
    }
    __syncthreads();

    // bin + accumulate buffered entries
    for (int i = t; i < (int)cnt; i += 256) {
        u32 kk = (u32)(S[i] >> 1);
        u32 ac = (u32)(S[i] & 1ull);
        u32 b = bucket_of(kk);
        int bin = 0;
        #pragma unroll
        for (int j = 0; j < NB; j++)
            bin += ((b > sB[j]) || (b == sB[j] && kk > sKj[j])) ? 1 : 0;
        u64 q = (u64)(__uint_as_float(kk) * 4294967296.0f);
        atomicAdd(&bc[bin], (unsigned long long)q);
        atomicAdd(&ba[bin], ac);
    }
    __syncthreads();

    if (t == 0) {
        double ece = 0.0;
        for (int b = 0; b < NBINS; b++) {
            u64 cq = confQ[b] + (u64)bc[b];
            u32 ac = accCnt[b] + ba[b];
            double cm = (double)cq * (1.0 / 4294967296.0) / (double)W;
            double am = (double)ac / (double)W;
            ece += fabs(cm - am);
            out[1 + b] = (float)am;
        }
        out[0] = (float)(ece * (double)W / (double)N);
    }
}

extern "C" void kernel_launch(void* const* d_in, const int* in_sizes, int n_in,
                              void* d_out, int out_size, void* d_ws, size_t ws_size,
                              hipStream_t stream) {
    const float* logits = (const float*)d_in[0];
    const int*   labels = (const int*)d_in[1];
    int N = in_sizes[1];
    int C = in_sizes[0] / N;
    float* out = (float*)d_out;

    u8* ws = (u8*)d_ws;
    u32* keys = (u32*)ws;                                   // 4N
    u8*  accb = ws + (size_t)4 * N;                         // N
    size_t aux = ((size_t)5 * N + 255) & ~(size_t)255;
    // zero-initialized region:
    u64* confQ   = (u64*)(ws + aux);                        // 160
    u32* accCnt  = (u32*)(ws + aux + 160);                  // 80  -> 240
    u32* listCnt = (u32*)(ws + aux + 240);                  // 4   -> 256 (pad)
    u32* hist    = (u32*)(ws + aux + 256);                  // 229376 -> 229632
    u32* meta    = (u32*)(ws + aux + 229632);               // 2*NB*4 = 152 -> 229784
    size_t zbytes = 229784;
    size_t loff = (aux + zbytes + 255) & ~(size_t)255;
    u64* list    = (u64*)(ws + loff);                       // LISTCAP*8 = 16 KB

    hipMemsetAsync(ws + aux, 0, zbytes, stream);

    u32 W = (u32)(N / NBINS);

    if (C == 100) {
        int blocks1 = (N + 15) / 16;  // 16 rows/block: 4 waves x 4 row-groups
        k1_conf100<<<blocks1, 256, 0, stream>>>(logits, labels, keys, accb, hist, N);
    } else {
        int blocks1 = (N + 255) / 256;
        k1_generic<<<blocks1, 256, 0, stream>>>(logits, labels, keys, accb, hist, N, C);
    }
    k2_scan  <<<1, 1024, 0, stream>>>(hist, meta, W);
    k37_accum<<<512, 256, 0, stream>>>(keys, accb, meta, confQ, accCnt, list, listCnt, N);
    k48_final<<<1, 256, 0, stream>>>(list, listCnt, meta, confQ, accCnt, out, W, N);
}

// Round 10
// 157.733 us; speedup vs baseline: 1.5692x; 1.5692x over previous
//
#include <hip/hip_runtime.h>
#include <stdint.h>

typedef uint32_t u32;
typedef uint64_t u64;
typedef uint8_t  u8;

#define KEY_MIN   0x3C000000u   /* conf = max softmax >= 1/C = 0.01 > 2^-7 */
#define SUBSHIFT  10
#define NBUCK     57344         /* (0x3F800000 - 0x3C000000) >> 10 */
#define CHUNKS    224           /* NBUCK / 256 */
#define NBINS     20
#define NB        19

__device__ __forceinline__ u32 bucket_of(u32 key) {
    if (key < KEY_MIN) return 0u;
    u32 b = (key - KEY_MIN) >> SUBSHIFT;
    return b < (u32)NBUCK ? b : (u32)(NBUCK - 1);
}

// ---------------- K1 (C==100): 16 lanes per row, coalesced (R4 champion) ------
__global__ __launch_bounds__(256) void k1_conf100(
        const float* __restrict__ logits, const int* __restrict__ labels,
        u32* __restrict__ keys, u8* __restrict__ accb, u32* __restrict__ hist,
        int N) {
    const int C4 = 25;
    int lane = threadIdx.x & 63;
    int wid  = (blockIdx.x * (blockDim.x >> 6)) + (threadIdx.x >> 6);
    int g    = lane >> 4;
    int sub  = lane & 15;
    int r    = wid * 4 + g;
    if (r >= N) return;

    const float4* row4 = (const float4*)(logits + (size_t)r * 100);
    float4 v0 = row4[sub];
    float4 v1;
    bool has2 = (sub + 16) < C4;
    if (has2) v1 = row4[sub + 16];
    else      v1 = make_float4(-3.4e38f, -3.4e38f, -3.4e38f, -3.4e38f);

    float m = v0.x; int am = 4 * sub;
    if (v0.y > m) { m = v0.y; am = 4 * sub + 1; }
    if (v0.z > m) { m = v0.z; am = 4 * sub + 2; }
    if (v0.w > m) { m = v0.w; am = 4 * sub + 3; }
    int b2 = 64 + 4 * sub;
    if (v1.x > m) { m = v1.x; am = b2; }
    if (v1.y > m) { m = v1.y; am = b2 + 1; }
    if (v1.z > m) { m = v1.z; am = b2 + 2; }
    if (v1.w > m) { m = v1.w; am = b2 + 3; }

    #pragma unroll
    for (int off = 8; off >= 1; off >>= 1) {
        float om = __shfl_xor(m, off);
        int   oa = __shfl_xor(am, off);
        if (om > m || (om == m && oa < am)) { m = om; am = oa; }
    }

    float s = __expf(v0.x - m) + __expf(v0.y - m) + __expf(v0.z - m) + __expf(v0.w - m);
    if (has2) s += __expf(v1.x - m) + __expf(v1.y - m) + __expf(v1.z - m) + __expf(v1.w - m);
    #pragma unroll
    for (int off = 8; off >= 1; off >>= 1) s += __shfl_xor(s, off);

    if (sub == 0) {
        float conf = 1.0f / s;
        u32 key = __float_as_uint(conf);
        keys[r] = key;
        accb[r] = (labels[r] == am) ? (u8)1 : (u8)0;
        atomicAdd(&hist[bucket_of(key)], 1u);
    }
}

// ---------------- K1 generic fallback -----------------------------------------
__global__ __launch_bounds__(256) void k1_generic(
        const float* __restrict__ logits, const int* __restrict__ labels,
        u32* __restrict__ keys, u8* __restrict__ accb, u32* __restrict__ hist,
        int N, int C) {
    int i = blockIdx.x * blockDim.x + threadIdx.x;
    if (i >= N) return;
    const float* row = logits + (size_t)i * (size_t)C;
    float m = -3.4e38f, s = 0.f;
    int am = 0;
    for (int c = 0; c < C; c++) {
        float v = row[c];
        float nm = fmaxf(m, v); am = (v > m) ? c : am;
        s = s * __expf(m - nm) + __expf(v - nm); m = nm;
    }
    float conf = 1.0f / s;
    u32 key = __float_as_uint(conf);
    keys[i] = key;
    accb[i] = (labels[i] == am) ? (u8)1 : (u8)0;
    atomicAdd(&hist[bucket_of(key)], 1u);
}

// meta: 0..18 bBucket | 19..37 bOff
// ---------------- K2a: coalesced per-chunk sums (224 blocks x 256) ------------
__global__ __launch_bounds__(256) void k2a_sums(
        const u32* __restrict__ hist, u32* __restrict__ partial) {
    int t = threadIdx.x, b = blockIdx.x;
    u32 v = hist[b * 256 + t];
    #pragma unroll
    for (int off = 32; off >= 1; off >>= 1) v += __shfl_xor(v, off);
    __shared__ u32 ws[4];
    if ((t & 63) == 0) ws[t >> 6] = v;
    __syncthreads();
    if (t == 0) partial[b] = ws[0] + ws[1] + ws[2] + ws[3];
}

// ---------------- K2b: locate boundary buckets (1 block, barrier-light) -------
__global__ __launch_bounds__(256) void k2b_locate(
        const u32* __restrict__ hist, const u32* __restrict__ partial,
        u32* __restrict__ meta, u32 W) {
    __shared__ u32 excl[CHUNKS + 1];
    int t = threadIdx.x;
    int lane = t & 63, w = t >> 6;
    if (w == 0) {                         // wave 0: shfl-scan the 224 partials
        u32 carry = 0;
        for (int q = 0; q < CHUNKS; q += 64) {
            u32 v = (q + lane < CHUNKS) ? partial[q + lane] : 0u;
            u32 inc = v;
            #pragma unroll
            for (int d = 1; d < 64; d <<= 1) {
                u32 x = __shfl_up(inc, d);
                if (lane >= d) inc += x;
            }
            if (q + lane < CHUNKS) excl[q + lane] = carry + inc - v;
            carry += __shfl(inc, 63);
        }
        if (lane == 0) excl[CHUNKS] = carry;   // == N
    }
    __syncthreads();
    // wave w handles boundaries j = w, w+4, ... (each wave independent)
    for (int j = w; j < NB; j += 4) {
        u32 r = (u32)(j + 1) * W;
        int lo = 0, hi = CHUNKS - 1;          // first c with excl[c+1] >= r
        while (lo < hi) {
            int mid = (lo + hi) >> 1;
            if (excl[mid + 1] < r) lo = mid + 1; else hi = mid;
        }
        int c = lo;                           // excl[c] < r <= excl[c+1]
        u32 cum = excl[c];
        for (int q = 0; q < 256; q += 64) {   // wave-scan the chunk's 256 buckets
            u32 v = hist[c * 256 + q + lane];
            u32 inc = v;
            #pragma unroll
            for (int d = 1; d < 64; d <<= 1) {
                u32 x = __shfl_up(inc, d);
                if (lane >= d) inc += x;
            }
            u32 myExcl = cum + inc - v;
            if (v && myExcl < r && r <= myExcl + v) {
                meta[j] = (u32)(c * 256 + q + lane);   // boundary bucket
                meta[NB + j] = r - myExcl;             // rank within bucket (>=1)
            }
            cum += __shfl(inc, 63);
        }
    }
}

// ---------------- K3: sub-histogram (low 10 bits) of boundary buckets ---------
__global__ __launch_bounds__(256) void k3_subhist(
        const u32* __restrict__ keys, const u32* __restrict__ meta,
        u32* __restrict__ subhist, int N) {
    __shared__ u32 sB[NB];
    if (threadIdx.x < NB) sB[threadIdx.x] = meta[threadIdx.x];
    __syncthreads();
    int total4 = N >> 2;
    const uint4* k4 = (const uint4*)keys;
    for (int i = blockIdx.x * blockDim.x + threadIdx.x; i < total4;
         i += gridDim.x * blockDim.x) {
        uint4 kv = k4[i];
        u32 ks[4] = {kv.x, kv.y, kv.z, kv.w};
        #pragma unroll
        for (int e = 0; e < 4; e++) {
            u32 b = bucket_of(ks[e]);
            #pragma unroll
            for (int j = 0; j < NB; j++)
                if (b == sB[j]) atomicAdd(&subhist[j * 1024 + (ks[e] & 1023u)], 1u);
        }
    }
    for (int i = (total4 << 2) + blockIdx.x * blockDim.x + threadIdx.x; i < N;
         i += gridDim.x * blockDim.x) {
        u32 k = keys[i];
        u32 b = bucket_of(k);
        for (int j = 0; j < NB; j++)
            if (b == sB[j]) atomicAdd(&subhist[j * 1024 + (k & 1023u)], 1u);
    }
}

// ---------------- K4: resolve exact threshold keys (19 blocks x 256) ----------
__global__ void k4_resolve(const u32* __restrict__ subhist, u32* __restrict__ meta) {
    int j = blockIdx.x;
    int t = threadIdx.x;
    __shared__ u32 sh[256];
    u32 v[4];
    #pragma unroll
    for (int k = 0; k < 4; k++) v[k] = subhist[j * 1024 + t * 4 + k];
    u32 tsum = v[0] + v[1] + v[2] + v[3];
    sh[t] = tsum; __syncthreads();
    for (int d = 1; d < 256; d <<= 1) {
        u32 x = (t >= d) ? sh[t - d] : 0u;
        __syncthreads(); sh[t] += x; __syncthreads();
    }
    u32 run = sh[t] - tsum;
    u32 off = meta[NB + j];
    u32 bkt = meta[j];
    #pragma unroll
    for (int k = 0; k < 4; k++) {
        if (run < off && off <= run + v[k])
            meta[2 * NB + j] = KEY_MIN + (bkt << SUBSHIFT) + (u32)(t * 4 + k);
        run += v[k];
    }
}

// ---------------- K7: per-bin exact accumulation (per-wave LDS bins) ----------
__global__ __launch_bounds__(256) void k7_accum(
        const u32* __restrict__ keys, const u8* __restrict__ accb,
        const u32* __restrict__ meta, u64* __restrict__ confQ,
        u32* __restrict__ accCnt, int N) {
    __shared__ unsigned long long lc[4][NBINS];
    __shared__ u32 la[4][NBINS];
    __shared__ u32 sK[NB];
    int t = threadIdx.x;
    int w = t >> 6;
    if (t < 4 * NBINS) { lc[t / NBINS][t % NBINS] = 0ull; la[t / NBINS][t % NBINS] = 0u; }
    if (t < NB) sK[t] = meta[2 * NB + t];
    __syncthreads();
    int total4 = N >> 2;
    const uint4*  k4 = (const uint4*)keys;
    const uchar4* a4 = (const uchar4*)accb;
    for (int i = blockIdx.x * blockDim.x + t; i < total4; i += gridDim.x * blockDim.x) {
        uint4  kv = k4[i];
        uchar4 av = a4[i];
        u32 ks[4] = {kv.x, kv.y, kv.z, kv.w};
        u32 as[4] = {av.x, av.y, av.z, av.w};
        #pragma unroll
        for (int e = 0; e < 4; e++) {
            int bin = 0;
            #pragma unroll
            for (int j = 0; j < NB; j++) bin += (ks[e] > sK[j]) ? 1 : 0;
            u64 q = (u64)(__uint_as_float(ks[e]) * 4294967296.0f);  // exact shift
            atomicAdd(&lc[w][bin], (unsigned long long)q);
            atomicAdd(&la[w][bin], as[e]);
        }
    }
    for (int i = (total4 << 2) + blockIdx.x * blockDim.x + t; i < N;
         i += gridDim.x * blockDim.x) {
        u32 k = keys[i];
        int bin = 0;
        for (int j = 0; j < NB; j++) bin += (k > sK[j]) ? 1 : 0;
        u64 q = (u64)(__uint_as_float(k) * 4294967296.0f);
        atomicAdd(&lc[w][bin], (unsigned long long)q);
        atomicAdd(&la[w][bin], (u32)accb[i]);
    }
    __syncthreads();
    if (t < NBINS) {
        unsigned long long cq = lc[0][t] + lc[1][t] + lc[2][t] + lc[3][t];
        u32 ac = la[0][t] + la[1][t] + la[2][t] + la[3][t];
        if (cq) atomicAdd((unsigned long long*)&confQ[t], cq);
        if (ac) atomicAdd(&accCnt[t], ac);
    }
}

// ---------------- K8: final ECE -----------------------------------------------
__global__ void k8_final(const u64* __restrict__ confQ, const u32* __restrict__ accCnt,
                         float* __restrict__ out, int W, int N) {
    if (threadIdx.x == 0 && blockIdx.x == 0) {
        double ece = 0.0;
        for (int b = 0; b < NBINS; b++) {
            double cm = (double)confQ[b] * (1.0 / 4294967296.0) / (double)W;
            double am = (double)accCnt[b] / (double)W;
            ece += fabs(cm - am);
            out[1 + b] = (float)am;
        }
        out[0] = (float)(ece * (double)W / (double)N);
    }
}

extern "C" void kernel_launch(void* const* d_in, const int* in_sizes, int n_in,
                              void* d_out, int out_size, void* d_ws, size_t ws_size,
                              hipStream_t stream) {
    const float* logits = (const float*)d_in[0];
    const int*   labels = (const int*)d_in[1];
    int N = in_sizes[1];
    int C = in_sizes[0] / N;
    float* out = (float*)d_out;

    u8* ws = (u8*)d_ws;
    u32* keys = (u32*)ws;                                   // 4N
    u8*  accb = ws + (size_t)4 * N;                         // N
    size_t aux = ((size_t)5 * N + 255) & ~(size_t)255;
    // zero-initialized region:
    u64* confQ   = (u64*)(ws + aux);                        // 160
    u32* accCnt  = (u32*)(ws + aux + 160);                  // 80   -> 240 (+16 pad)
    u32* hist    = (u32*)(ws + aux + 256);                  // 229376 -> 229632
    u32* subhist = (u32*)(ws + aux + 229632);               // 77824  -> 307456
    u32* meta    = (u32*)(ws + aux + 307456);               // 3*NB*4 = 228
    size_t zbytes = 307456 + 228;
    // non-zeroed scratch (written before read):
    size_t poff = (aux + zbytes + 255) & ~(size_t)255;
    u32* partial = (u32*)(ws + poff);                       // CHUNKS*4 = 896

    hipMemsetAsync(ws + aux, 0, zbytes, stream);

    u32 W = (u32)(N / NBINS);

    if (C == 100) {
        int blocks1 = (N + 15) / 16;  // 16 rows/block: 4 waves x 4 row-groups
        k1_conf100<<<blocks1, 256, 0, stream>>>(logits, labels, keys, accb, hist, N);
    } else {
        int blocks1 = (N + 255) / 256;
        k1_generic<<<blocks1, 256, 0, stream>>>(logits, labels, keys, accb, hist, N, C);
    }
    k2a_sums  <<<CHUNKS, 256, 0, stream>>>(hist, partial);
    k2b_locate<<<1, 256, 0, stream>>>(hist, partial, meta, W);
    k3_subhist<<<1024, 256, 0, stream>>>(keys, meta, subhist, N);
    k4_resolve<<<NB, 256, 0, stream>>>(subhist, meta);
    k7_accum  <<<1024, 256, 0, stream>>>(keys, accb, meta, confQ, accCnt, N);
    k8_final  <<<1, 64, 0, stream>>>(confQ, accCnt, out, (int)W, N);
}

// Round 11
// 157.679 us; speedup vs baseline: 1.5698x; 1.0003x over previous
//
#include <hip/hip_runtime.h>
#include <stdint.h>

typedef uint32_t u32;
typedef uint64_t u64;
typedef uint8_t  u8;

#define KEY_MIN   0x3C000000u   /* conf = max softmax >= 1/C = 0.01 > 2^-7 */
#define SUBSHIFT  10
#define NBUCK     57344         /* (0x3F800000 - 0x3C000000) >> 10 */
#define CHUNKS    224           /* NBUCK / 256 */
#define NBINS     20
#define NB        19

__device__ __forceinline__ u32 bucket_of(u32 key) {
    if (key < KEY_MIN) return 0u;
    u32 b = (key - KEY_MIN) >> SUBSHIFT;
    return b < (u32)NBUCK ? b : (u32)(NBUCK - 1);
}

// DPP row-rotate (within 16-lane row), full-rate VALU cross-lane.
// ctrl: ROW_ROR:N = 0x120 + N.
template<int CTRL>
__device__ __forceinline__ float dppf(float v) {
    int i = __float_as_int(v);
    int r = __builtin_amdgcn_update_dpp(i, i, CTRL, 0xF, 0xF, false);
    return __int_as_float(r);
}

// ---------------- K1 (C==100): 16 lanes/row, DPP reduce, no argmax chain ------
// acc = (row[label] == rowmax): owner lane compares, wave ballot collects.
// Differs from np argmax only on exact duplicate-max ties at the label
// (expected <<1 row in 1M; <=2e-5 effect on a bin mean).
__global__ __launch_bounds__(256) void k1_conf100(
        const float* __restrict__ logits, const int* __restrict__ labels,
        u32* __restrict__ keys, u8* __restrict__ accb, u32* __restrict__ hist,
        int N) {
    int lane = threadIdx.x & 63;
    int wid  = (blockIdx.x * (blockDim.x >> 6)) + (threadIdx.x >> 6);
    int g    = lane >> 4;
    int sub  = lane & 15;
    int r    = wid * 4 + g;
    if (r >= N) return;

    const float4* row4 = (const float4*)(logits + (size_t)r * 100);
    float4 v0 = row4[sub];
    float4 v1;
    bool has2 = sub < 9;                      // 25 float4/row: sub and sub+16
    if (has2) v1 = row4[sub + 16];
    else      v1 = make_float4(-3.4e38f, -3.4e38f, -3.4e38f, -3.4e38f);

    // in-lane max (tree; compiler fuses to v_max3)
    float m = fmaxf(fmaxf(fmaxf(v0.x, v0.y), fmaxf(v0.z, v0.w)),
                    fmaxf(fmaxf(v1.x, v1.y), fmaxf(v1.z, v1.w)));

    // 16-lane max reduce via DPP rotations (all lanes get row max)
    m = fmaxf(m, dppf<0x128>(m));   // ror 8
    m = fmaxf(m, dppf<0x124>(m));   // ror 4
    m = fmaxf(m, dppf<0x122>(m));   // ror 2
    m = fmaxf(m, dppf<0x121>(m));   // ror 1

    // accuracy: owner lane holds row[label]; compare with max; ballot
    int lbl = labels[r];
    bool inHi = lbl >= 64;
    int owner = inHi ? ((lbl - 64) >> 2) : (lbl >> 2);
    int comp  = lbl & 3;
    float4 vv = inHi ? v1 : v0;
    float cand = (comp == 0) ? vv.x : (comp == 1) ? vv.y : (comp == 2) ? vv.z : vv.w;
    bool eq = (sub == owner) && (cand == m);
    unsigned long long bal = __ballot(eq);

    // sum of exp(v - m)
    float s = __expf(v0.x - m) + __expf(v0.y - m) + __expf(v0.z - m) + __expf(v0.w - m);
    if (has2) s += __expf(v1.x - m) + __expf(v1.y - m) + __expf(v1.z - m) + __expf(v1.w - m);

    // 16-lane sum reduce via DPP rotations (lane sub==0's order is fixed -> deterministic)
    s += dppf<0x128>(s);
    s += dppf<0x124>(s);
    s += dppf<0x122>(s);
    s += dppf<0x121>(s);

    if (sub == 0) {
        float conf = 1.0f / s;
        u32 key = __float_as_uint(conf);
        keys[r] = key;
        accb[r] = ((bal >> (g * 16)) & 0xFFFFull) ? (u8)1 : (u8)0;
        atomicAdd(&hist[bucket_of(key)], 1u);
    }
}

// ---------------- K1 generic fallback -----------------------------------------
__global__ __launch_bounds__(256) void k1_generic(
        const float* __restrict__ logits, const int* __restrict__ labels,
        u32* __restrict__ keys, u8* __restrict__ accb, u32* __restrict__ hist,
        int N, int C) {
    int i = blockIdx.x * blockDim.x + threadIdx.x;
    if (i >= N) return;
    const float* row = logits + (size_t)i * (size_t)C;
    float m = -3.4e38f, s = 0.f;
    int am = 0;
    for (int c = 0; c < C; c++) {
        float v = row[c];
        float nm = fmaxf(m, v); am = (v > m) ? c : am;
        s = s * __expf(m - nm) + __expf(v - nm); m = nm;
    }
    float conf = 1.0f / s;
    u32 key = __float_as_uint(conf);
    keys[i] = key;
    accb[i] = (labels[i] == am) ? (u8)1 : (u8)0;
    atomicAdd(&hist[bucket_of(key)], 1u);
}

// meta: 0..18 bBucket | 19..37 bOff
// ---------------- K2a: coalesced per-chunk sums (224 blocks x 256) ------------
__global__ __launch_bounds__(256) void k2a_sums(
        const u32* __restrict__ hist, u32* __restrict__ partial) {
    int t = threadIdx.x, b = blockIdx.x;
    u32 v = hist[b * 256 + t];
    #pragma unroll
    for (int off = 32; off >= 1; off >>= 1) v += __shfl_xor(v, off);
    __shared__ u32 ws[4];
    if ((t & 63) == 0) ws[t >> 6] = v;
    __syncthreads();
    if (t == 0) partial[b] = ws[0] + ws[1] + ws[2] + ws[3];
}

// ---------------- K2b: locate boundary buckets (1 block, barrier-light) -------
__global__ __launch_bounds__(256) void k2b_locate(
        const u32* __restrict__ hist, const u32* __restrict__ partial,
        u32* __restrict__ meta, u32 W) {
    __shared__ u32 excl[CHUNKS + 1];
    int t = threadIdx.x;
    int lane = t & 63, w = t >> 6;
    if (w == 0) {                         // wave 0: shfl-scan the 224 partials
        u32 carry = 0;
        for (int q = 0; q < CHUNKS; q += 64) {
            u32 v = (q + lane < CHUNKS) ? partial[q + lane] : 0u;
            u32 inc = v;
            #pragma unroll
            for (int d = 1; d < 64; d <<= 1) {
                u32 x = __shfl_up(inc, d);
                if (lane >= d) inc += x;
            }
            if (q + lane < CHUNKS) excl[q + lane] = carry + inc - v;
            carry += __shfl(inc, 63);
        }
        if (lane == 0) excl[CHUNKS] = carry;   // == N
    }
    __syncthreads();
    // wave w handles boundaries j = w, w+4, ...
    for (int j = w; j < NB; j += 4) {
        u32 r = (u32)(j + 1) * W;
        int lo = 0, hi = CHUNKS - 1;          // first c with excl[c+1] >= r
        while (lo < hi) {
            int mid = (lo + hi) >> 1;
            if (excl[mid + 1] < r) lo = mid + 1; else hi = mid;
        }
        int c = lo;                           // excl[c] < r <= excl[c+1]
        u32 cum = excl[c];
        for (int q = 0; q < 256; q += 64) {   // wave-scan the chunk's 256 buckets
            u32 v = hist[c * 256 + q + lane];
            u32 inc = v;
            #pragma unroll
            for (int d = 1; d < 64; d <<= 1) {
                u32 x = __shfl_up(inc, d);
                if (lane >= d) inc += x;
            }
            u32 myExcl = cum + inc - v;
            if (v && myExcl < r && r <= myExcl + v) {
                meta[j] = (u32)(c * 256 + q + lane);   // boundary bucket
                meta[NB + j] = r - myExcl;             // rank within bucket (>=1)
            }
            cum += __shfl(inc, 63);
        }
    }
}

// ---------------- K3: sub-histogram (low 10 bits) of boundary buckets ---------
__global__ __launch_bounds__(256) void k3_subhist(
        const u32* __restrict__ keys, const u32* __restrict__ meta,
        u32* __restrict__ subhist, int N) {
    __shared__ u32 sB[NB];
    if (threadIdx.x < NB) sB[threadIdx.x] = meta[threadIdx.x];
    __syncthreads();
    int total4 = N >> 2;
    const uint4* k4 = (const uint4*)keys;
    for (int i = blockIdx.x * blockDim.x + threadIdx.x; i < total4;
         i += gridDim.x * blockDim.x) {
        uint4 kv = k4[i];
        u32 ks[4] = {kv.x, kv.y, kv.z, kv.w};
        #pragma unroll
        for (int e = 0; e < 4; e++) {
            u32 b = bucket_of(ks[e]);
            #pragma unroll
            for (int j = 0; j < NB; j++)
                if (b == sB[j]) atomicAdd(&subhist[j * 1024 + (ks[e] & 1023u)], 1u);
        }
    }
    for (int i = (total4 << 2) + blockIdx.x * blockDim.x + threadIdx.x; i < N;
         i += gridDim.x * blockDim.x) {
        u32 k = keys[i];
        u32 b = bucket_of(k);
        for (int j = 0; j < NB; j++)
            if (b == sB[j]) atomicAdd(&subhist[j * 1024 + (k & 1023u)], 1u);
    }
}

// ---------------- K4: resolve exact threshold keys (19 blocks x 256) ----------
__global__ void k4_resolve(const u32* __restrict__ subhist, u32* __restrict__ meta) {
    int j = blockIdx.x;
    int t = threadIdx.x;
    __shared__ u32 sh[256];
    u32 v[4];
    #pragma unroll
    for (int k = 0; k < 4; k++) v[k] = subhist[j * 1024 + t * 4 + k];
    u32 tsum = v[0] + v[1] + v[2] + v[3];
    sh[t] = tsum; __syncthreads();
    for (int d = 1; d < 256; d <<= 1) {
        u32 x = (t >= d) ? sh[t - d] : 0u;
        __syncthreads(); sh[t] += x; __syncthreads();
    }
    u32 run = sh[t] - tsum;
    u32 off = meta[NB + j];
    u32 bkt = meta[j];
    #pragma unroll
    for (int k = 0; k < 4; k++) {
        if (run < off && off <= run + v[k])
            meta[2 * NB + j] = KEY_MIN + (bkt << SUBSHIFT) + (u32)(t * 4 + k);
        run += v[k];
    }
}

// ---------------- K7: per-bin exact accumulation (per-wave LDS bins) ----------
__global__ __launch_bounds__(256) void k7_accum(
        const u32* __restrict__ keys, const u8* __restrict__ accb,
        const u32* __restrict__ meta, u64* __restrict__ confQ,
        u32* __restrict__ accCnt, int N) {
    __shared__ unsigned long long lc[4][NBINS];
    __shared__ u32 la[4][NBINS];
    __shared__ u32 sK[NB];
    int t = threadIdx.x;
    int w = t >> 6;
    if (t < 4 * NBINS) { lc[t / NBINS][t % NBINS] = 0ull; la[t / NBINS][t % NBINS] = 0u; }
    if (t < NB) sK[t] = meta[2 * NB + t];
    __syncthreads();
    int total4 = N >> 2;
    const uint4*  k4 = (const uint4*)keys;
    const uchar4* a4 = (const uchar4*)accb;
    for (int i = blockIdx.x * blockDim.x + t; i < total4; i += gridDim.x * blockDim.x) {
        uint4  kv = k4[i];
        uchar4 av = a4[i];
        u32 ks[4] = {kv.x, kv.y, kv.z, kv.w};
        u32 as[4] = {av.x, av.y, av.z, av.w};
        #pragma unroll
        for (int e = 0; e < 4; e++) {
            int bin = 0;
            #pragma unroll
            for (int j = 0; j < NB; j++) bin += (ks[e] > sK[j]) ? 1 : 0;
            u64 q = (u64)(__uint_as_float(ks[e]) * 4294967296.0f);  // exact shift
            atomicAdd(&lc[w][bin], (unsigned long long)q);
            atomicAdd(&la[w][bin], as[e]);
        }
    }
    for (int i = (total4 << 2) + blockIdx.x * blockDim.x + t; i < N;
         i += gridDim.x * blockDim.x) {
        u32 k = keys[i];
        int bin = 0;
        for (int j = 0; j < NB; j++) bin += (k > sK[j]) ? 1 : 0;
        u64 q = (u64)(__uint_as_float(k) * 4294967296.0f);
        atomicAdd(&lc[w][bin], (unsigned long long)q);
        atomicAdd(&la[w][bin], (u32)accb[i]);
    }
    __syncthreads();
    if (t < NBINS) {
        unsigned long long cq = lc[0][t] + lc[1][t] + lc[2][t] + lc[3][t];
        u32 ac = la[0][t] + la[1][t] + la[2][t] + la[3][t];
        if (cq) atomicAdd((unsigned long long*)&confQ[t], cq);
        if (ac) atomicAdd(&accCnt[t], ac);
    }
}

// ---------------- K8: final ECE -----------------------------------------------
__global__ void k8_final(const u64* __restrict__ confQ, const u32* __restrict__ accCnt,
                         float* __restrict__ out, int W, int N) {
    if (threadIdx.x == 0 && blockIdx.x == 0) {
        double ece = 0.0;
        for (int b = 0; b < NBINS; b++) {
            double cm = (double)confQ[b] * (1.0 / 4294967296.0) / (double)W;
            double am = (double)accCnt[b] / (double)W;
            ece += fabs(cm - am);
            out[1 + b] = (float)am;
        }
        out[0] = (float)(ece * (double)W / (double)N);
    }
}

extern "C" void kernel_launch(void* const* d_in, const int* in_sizes, int n_in,
                              void* d_out, int out_size, void* d_ws, size_t ws_size,
                              hipStream_t stream) {
    const float* logits = (const float*)d_in[0];
    const int*   labels = (const int*)d_in[1];
    int N = in_sizes[1];
    int C = in_sizes[0] / N;
    float* out = (float*)d_out;

    u8* ws = (u8*)d_ws;
    u32* keys = (u32*)ws;                                   // 4N
    u8*  accb = ws + (size_t)4 * N;                         // N
    size_t aux = ((size_t)5 * N + 255) & ~(size_t)255;
    // zero-initialized region:
    u64* confQ   = (u64*)(ws + aux);                        // 160
    u32* accCnt  = (u32*)(ws + aux + 160);                  // 80   -> 240 (+16 pad)
    u32* hist    = (u32*)(ws + aux + 256);                  // 229376 -> 229632
    u32* subhist = (u32*)(ws + aux + 229632);               // 77824  -> 307456
    u32* meta    = (u32*)(ws + aux + 307456);               // 3*NB*4 = 228
    size_t zbytes = 307456 + 228;
    // non-zeroed scratch (written before read):
    size_t poff = (aux + zbytes + 255) & ~(size_t)255;
    u32* partial = (u32*)(ws + poff);                       // CHUNKS*4 = 896

    hipMemsetAsync(ws + aux, 0, zbytes, stream);

    u32 W = (u32)(N / NBINS);

    if (C == 100) {
        int blocks1 = (N + 15) / 16;  // 16 rows/block: 4 waves x 4 row-groups
        k1_conf100<<<blocks1, 256, 0, stream>>>(logits, labels, keys, accb, hist, N);
    } else {
        int blocks1 = (N + 255) / 256;
        k1_generic<<<blocks1, 256, 0, stream>>>(logits, labels, keys, accb, hist, N, C);
    }
    k2a_sums  <<<CHUNKS, 256, 0, stream>>>(hist, partial);
    k2b_locate<<<1, 256, 0, stream>>>(hist, partial, meta, W);
    k3_subhist<<<1024, 256, 0, stream>>>(keys, meta, subhist, N);
    k4_resolve<<<NB, 256, 0, stream>>>(subhist, meta);
    k7_accum  <<<1024, 256, 0, stream>>>(keys, accb, meta, confQ, accCnt, N);
    k8_final  <<<1, 64, 0, stream>>>(confQ, accCnt, out, (int)W, N);
}